// Round 5
// baseline (1520.622 us; speedup 1.0000x reference)
//
#include <hip/hip_runtime.h>

// Problem dims
#define BB 64
#define TT 80
#define EE 100
#define UU 2048
#define NWG 192

typedef float f32x4 __attribute__((ext_vector_type(4)));
typedef unsigned int u32x4 __attribute__((ext_vector_type(4)));
typedef __bf16 bf16x8 __attribute__((ext_vector_type(8)));
typedef unsigned long long u64;

// ---- workspace layout (bytes) ----
#define XPROJ_OFF 0u              // bf16 [80][64][2048]  = 20,971,520
#define WPACK_OFF 20971520u       // bf16 packed [192][4(kq)][16(kt)][2(c)][64][8] = 25,165,824
#define H0_OFF    46137344u       // bf16 [2][64][2048] = 524,288
#define H1_OFF    46661632u       // bf16 [2][64][2048] = 524,288
#define PX_OFF    47185920u       // f32  [2][64][2048] = 1,048,576
#define H1F_OFF   48234496u       // f32  [64][2048]    = 524,288
#define BAR_OFF   48758784u       // int flags padded: 192 * 256 B = 49,152
#define WS_NEEDED 48807936u
#define ZERO_U4   166912          // (WS_NEEDED - H0_OFF)/16

#define LDS_BYTES 147968          // 131072 weights + 2*64*33*4 red

__device__ __forceinline__ unsigned short f2bf(float f) {
  unsigned int u = __float_as_uint(f);
  u += 0x7fffu + ((u >> 16) & 1u);
  return (unsigned short)(u >> 16);
}
__device__ __forceinline__ float bf2f(unsigned short h) {
  return __uint_as_float(((unsigned int)h) << 16);
}
__device__ __forceinline__ u64 pack4(float a, float b, float c, float d) {
  return (u64)f2bf(a) | ((u64)f2bf(b) << 16) | ((u64)f2bf(c) << 32) | ((u64)f2bf(d) << 48);
}
__device__ __forceinline__ bf16x8 u2b(u32x4 u) {
  union { u32x4 q; bf16x8 b; } x; x.q = u; return x.b;
}
__device__ __forceinline__ f32x4 u2f(u32x4 u) {
  union { u32x4 q; f32x4 f; } x; x.q = u; return x.f;
}

// coherent (device-scope, L1+L2 bypass) flag ops
__device__ __forceinline__ void st_flag(int* p, int v) {
  asm volatile("global_store_dword %0, %1, off sc0 sc1" :: "v"(p), "v"(v) : "memory");
}
__device__ __forceinline__ int ld_flag(const int* p) {
  int r;
  asm volatile("global_load_dword %0, %1, off sc0 sc1\n\ts_waitcnt vmcnt(0)"
               : "=v"(r) : "v"(p) : "memory");
  return r;
}

// -------------------- zero init --------------------
__global__ void zero_init(u32x4* __restrict__ p, int n) {
  u32x4 z = {0u, 0u, 0u, 0u};
  for (int i = blockIdx.x * blockDim.x + threadIdx.x; i < n; i += gridDim.x * blockDim.x)
    p[i] = z;
}

// -------------------- weight pack --------------------
// dest elem: wg*65536 + kq*16384 + kt*1024 + c*512 + lane*8 + j
// value = W[k][col], k = kq*512 + kt*32 + (lane>>4)*8 + j, col = wl*32 + c*16 + (lane&15)
// wg = L*64 + wl ; L in {Wh0, Wx1, Wh1}
__global__ __launch_bounds__(256) void pack_weights(
    const float* __restrict__ Wh0, const float* __restrict__ Wx1,
    const float* __restrict__ Wh1, unsigned short* __restrict__ wpack) {
  __shared__ float tile[32][33];
  const int bb = blockIdx.x;             // 0..383
  const int L = bb >> 7;
  const int rest = bb & 127;
  const int wl = rest >> 1;
  const int kh = rest & 1;               // k half (1024)
  const float* src = (L == 0) ? Wh0 : (L == 1) ? Wx1 : Wh1;
  const int tid = threadIdx.x;
  const int kr = tid >> 3, cqr = tid & 7;          // read mapping
  const int c = tid >> 7;                           // write mapping
  const int lane = (tid >> 1) & 63;
  const int jh = (tid & 1) << 2;
  const int l16 = lane & 15, lq = lane >> 4;
  const size_t wg = (size_t)(L << 6) + wl;

  for (int kc = 0; kc < 32; ++kc) {
    const int kq = (kh << 1) + (kc >> 4);
    const int kt = kc & 15;
    const int k0 = (kh << 10) + (kc << 5);
    float4 v = *(const float4*)&src[(size_t)(k0 + kr) * 2048u + (wl << 5) + (cqr << 2)];
    tile[kr][cqr * 4 + 0] = v.x;
    tile[kr][cqr * 4 + 1] = v.y;
    tile[kr][cqr * 4 + 2] = v.z;
    tile[kr][cqr * 4 + 3] = v.w;
    __syncthreads();
    ushort4 o;
    o.x = f2bf(tile[lq * 8 + jh + 0][c * 16 + l16]);
    o.y = f2bf(tile[lq * 8 + jh + 1][c * 16 + l16]);
    o.z = f2bf(tile[lq * 8 + jh + 2][c * 16 + l16]);
    o.w = f2bf(tile[lq * 8 + jh + 3][c * 16 + l16]);
    size_t doff = (wg << 16) + ((size_t)kq << 14) + ((size_t)kt << 10) + (c << 9) + (lane << 3) + jh;
    *(ushort4*)&wpack[doff] = o;
    __syncthreads();
  }
}

// -------------------- xproj = emb[inputs] @ Wx0 + b0 (bf16 out) --------------------
__global__ __launch_bounds__(256) void xproj_kernel(
    const int* __restrict__ inputs, const float* __restrict__ emb,
    const float* __restrict__ Wx0, const float* __restrict__ b0,
    unsigned short* __restrict__ xp) {
  __shared__ float X[64][100];
  __shared__ float Wl[100][64];
  __shared__ int idx[64];
  const int t = blockIdx.y, ut = blockIdx.x, tid = threadIdx.x;
  if (tid < 64) idx[tid] = inputs[tid * TT + t];
  __syncthreads();
  for (int i = tid; i < 6400; i += 256) {
    int b = i / 100, e = i - b * 100;
    X[b][e] = emb[(size_t)idx[b] * EE + e];
  }
  for (int i = tid; i < 6400; i += 256) {
    int e = i >> 6, u = i & 63;
    Wl[e][u] = Wx0[(size_t)e * UU + (ut << 6) + u];
  }
  __syncthreads();
  const int ul = tid & 63, bg = tid >> 6;
  float accv[16];
  const float bias = b0[(ut << 6) + ul];
#pragma unroll
  for (int q = 0; q < 16; ++q) accv[q] = bias;
  for (int e4 = 0; e4 < 100; e4 += 4) {
    float w0 = Wl[e4 + 0][ul], w1 = Wl[e4 + 1][ul], w2 = Wl[e4 + 2][ul], w3 = Wl[e4 + 3][ul];
#pragma unroll
    for (int q = 0; q < 16; ++q) {
      float4 x4 = *(const float4*)&X[bg * 16 + q][e4];
      accv[q] += w0 * x4.x + w1 * x4.y + w2 * x4.z + w3 * x4.w;
    }
  }
  unsigned short* dst = xp + ((size_t)t * 64u) * 2048u + (ut << 6);
#pragma unroll
  for (int q = 0; q < 16; ++q) dst[(size_t)(bg * 16 + q) * 2048u + ul] = f2bf(accv[q]);
}

// -------------------- persistent RNN --------------------
// 192 WGs: layer = wg>>6 (0: h0, 1: px = h0@Wx1+b1, 2: h1), wl = wg&63 -> cols [wl*32,+32)
// wave = K-quarter (disjoint A reads); cross-wave reduce via LDS (2-phase).
// A/px consumed via NORMAL cached loads + buffer_inv acquire; produced via sc0 sc1
// stores (straight to IC, L2 never dirty -> no writeback needed on release).
// superstep s: L0 -> h0[s] (s<80); L1 -> px[s-1] (1<=s<=80); L2 -> h1[s-2] (2<=s<=81)
__global__ __launch_bounds__(256, 1) void rnn_persistent(
    const unsigned short* __restrict__ xproj, const unsigned short* __restrict__ wpack,
    unsigned short* __restrict__ h0b, unsigned short* __restrict__ h1b,
    float* __restrict__ px, float* __restrict__ h1f,
    const float* __restrict__ b1, int* __restrict__ bar) {
  extern __shared__ char smem[];
  unsigned short* wlds = (unsigned short*)smem;   // 131072 B: [wave(kq)][kt][c][lane][8]
  float* red = (float*)(smem + 131072);           // 2*64*33*4 = 16896 B
  const int wg = blockIdx.x, tid = threadIdx.x;
  const int wave = tid >> 6, lane = tid & 63;
  const int layer = wg >> 6, wl = wg & 63;
  const int l16 = lane & 15, lq = lane >> 4;
  const int colb = wl << 5;

  // stage this WG's packed weights into LDS (once)
  {
    const u32x4* srcp = (const u32x4*)(wpack + ((size_t)wg << 16));
    u32x4* dstp = (u32x4*)smem;
    for (int i = tid; i < 8192; i += 256) dstp[i] = srcp[i];
  }
  __syncthreads();

  const unsigned short* wbase = wlds + (wave << 14) + (lane << 3);
  // A element offset (this wave's K-quarter): row = rg*16+l16, k = wave*512 + lq*8
  const int aoff = l16 * 2048 + (wave << 9) + (lq << 3);
  // epilogue items
  const int r0 = tid >> 3, cq = tid & 7;
  const int r1 = r0 + 32;

  for (int s = 0; s <= 81; ++s) {
    const bool active = (layer == 0) ? (s < 80) : (layer == 1) ? (s >= 1 && s <= 80) : (s >= 2);
    if (active) {
      // acquire: drop stale L1/L2 copies of h/px before cached re-reads.
      asm volatile("buffer_inv sc1\n\ts_waitcnt vmcnt(0)" ::: "memory");

      const unsigned short* Abuf =
          (layer == 2) ? (h1b + (((s - 3) & 1) * 131072))
                       : (h0b + (((s - 1) & 1) * 131072));
      const unsigned short* ap0 = Abuf + aoff;
      const unsigned short* ap1 = ap0 + 16 * 2048;
      const unsigned short* ap2 = ap0 + 32 * 2048;
      const unsigned short* ap3 = ap0 + 48 * 2048;

      u32x4 pxq0, pxq1;
      if (layer == 2) {
        const float* pxs = px + ((size_t)((s - 2) & 1) * 131072u);
        const float* pp0 = pxs + r0 * 2048 + colb + (cq << 2);
        const float* pp1 = pxs + r1 * 2048 + colb + (cq << 2);
        asm volatile("global_load_dwordx4 %0, %2, off\n\t"
                     "global_load_dwordx4 %1, %3, off"
                     : "=v"(pxq0), "=v"(pxq1) : "v"(pp0), "v"(pp1) : "memory");
      }

      u32x4 Asl[8][4];
      f32x4 c00 = {0,0,0,0}, c01 = {0,0,0,0}, c10 = {0,0,0,0}, c11 = {0,0,0,0};
      f32x4 c20 = {0,0,0,0}, c21 = {0,0,0,0}, c30 = {0,0,0,0}, c31 = {0,0,0,0};

#define ISSUE(sl, koff) \
      asm volatile("global_load_dwordx4 %0, %4, off offset:" #koff "\n\t" \
                   "global_load_dwordx4 %1, %5, off offset:" #koff "\n\t" \
                   "global_load_dwordx4 %2, %6, off offset:" #koff "\n\t" \
                   "global_load_dwordx4 %3, %7, off offset:" #koff \
                   : "=v"(Asl[sl][0]), "=v"(Asl[sl][1]), "=v"(Asl[sl][2]), "=v"(Asl[sl][3]) \
                   : "v"(ap0), "v"(ap1), "v"(ap2), "v"(ap3) : "memory")

      ISSUE(0, 0);   ISSUE(1, 64);  ISSUE(2, 128); ISSUE(3, 192);
      ISSUE(4, 256); ISSUE(5, 320); ISSUE(6, 384); ISSUE(7, 448);

      bf16x8 cb0 = *(const bf16x8*)(wbase);
      bf16x8 cb1 = *(const bf16x8*)(wbase + 512);

#define MFMA8(sl) \
      c00 = __builtin_amdgcn_mfma_f32_16x16x32_bf16(u2b(Asl[sl][0]), cb0, c00, 0, 0, 0); \
      c10 = __builtin_amdgcn_mfma_f32_16x16x32_bf16(u2b(Asl[sl][1]), cb0, c10, 0, 0, 0); \
      c20 = __builtin_amdgcn_mfma_f32_16x16x32_bf16(u2b(Asl[sl][2]), cb0, c20, 0, 0, 0); \
      c30 = __builtin_amdgcn_mfma_f32_16x16x32_bf16(u2b(Asl[sl][3]), cb0, c30, 0, 0, 0); \
      c01 = __builtin_amdgcn_mfma_f32_16x16x32_bf16(u2b(Asl[sl][0]), cb1, c01, 0, 0, 0); \
      c11 = __builtin_amdgcn_mfma_f32_16x16x32_bf16(u2b(Asl[sl][1]), cb1, c11, 0, 0, 0); \
      c21 = __builtin_amdgcn_mfma_f32_16x16x32_bf16(u2b(Asl[sl][2]), cb1, c21, 0, 0, 0); \
      c31 = __builtin_amdgcn_mfma_f32_16x16x32_bf16(u2b(Asl[sl][3]), cb1, c31, 0, 0, 0)

#define KTI(kt, vN, koff) { \
      asm volatile("s_waitcnt vmcnt(" #vN ")" ::: "memory"); \
      __builtin_amdgcn_sched_barrier(0); \
      bf16x8 nb0 = *(const bf16x8*)(wbase + (kt + 1) * 1024); \
      bf16x8 nb1 = *(const bf16x8*)(wbase + (kt + 1) * 1024 + 512); \
      MFMA8((kt) & 7); \
      ISSUE((kt) & 7, koff); \
      cb0 = nb0; cb1 = nb1; }

#define KTN(kt, vN) { \
      asm volatile("s_waitcnt vmcnt(" #vN ")" ::: "memory"); \
      __builtin_amdgcn_sched_barrier(0); \
      bf16x8 nb0 = cb0, nb1 = cb1; \
      if ((kt) < 15) { nb0 = *(const bf16x8*)(wbase + (kt + 1) * 1024); \
                       nb1 = *(const bf16x8*)(wbase + (kt + 1) * 1024 + 512); } \
      MFMA8((kt) & 7); \
      cb0 = nb0; cb1 = nb1; }

      KTI(0, 28, 512); KTI(1, 28, 576); KTI(2, 28, 640); KTI(3, 28, 704);
      KTI(4, 28, 768); KTI(5, 28, 832); KTI(6, 28, 896); KTI(7, 28, 960);
      KTN(8, 28); KTN(9, 24); KTN(10, 20); KTN(11, 16);
      KTN(12, 12); KTN(13, 8); KTN(14, 4); KTN(15, 0);

#undef ISSUE
#undef MFMA8
#undef KTI
#undef KTN

      // ---- cross-wave K reduction (2-phase) ----
#define WRROW(cv, rg, cc) { int bi = ((rg)*16 + lq*4)*33 + (cc)*16 + l16; \
      rb[bi] = cv[0]; rb[bi+33] = cv[1]; rb[bi+66] = cv[2]; rb[bi+99] = cv[3]; }
#define ADROW(cv, rg, cc) { int bi = ((rg)*16 + lq*4)*33 + (cc)*16 + l16; \
      rb[bi] += cv[0]; rb[bi+33] += cv[1]; rb[bi+66] += cv[2]; rb[bi+99] += cv[3]; }
      if (wave < 2) {
        float* rb = red + wave * 2112;
        WRROW(c00, 0, 0); WRROW(c10, 1, 0); WRROW(c20, 2, 0); WRROW(c30, 3, 0);
        WRROW(c01, 0, 1); WRROW(c11, 1, 1); WRROW(c21, 2, 1); WRROW(c31, 3, 1);
      }
      __syncthreads();
      if (wave >= 2) {
        float* rb = red + (wave - 2) * 2112;
        ADROW(c00, 0, 0); ADROW(c10, 1, 0); ADROW(c20, 2, 0); ADROW(c30, 3, 0);
        ADROW(c01, 0, 1); ADROW(c11, 1, 1); ADROW(c21, 2, 1); ADROW(c31, 3, 1);
      }
      __syncthreads();
#undef WRROW
#undef ADROW

      // ---- epilogue: 2 items/thread ----
      {
        const int gc = colb + (cq << 2);
        auto do_item = [&](int r, u32x4 pxq) {
          const int c0 = cq << 2;
          float v0 = red[r * 33 + c0 + 0] + red[2112 + r * 33 + c0 + 0];
          float v1 = red[r * 33 + c0 + 1] + red[2112 + r * 33 + c0 + 1];
          float v2 = red[r * 33 + c0 + 2] + red[2112 + r * 33 + c0 + 2];
          float v3 = red[r * 33 + c0 + 3] + red[2112 + r * 33 + c0 + 3];
          const size_t ro = ((size_t)r << 11) + gc;
          if (layer == 0) {
            u64 xq = *(const u64*)(xproj + (size_t)s * 131072u + ro);
            v0 = tanhf(v0 + bf2f((unsigned short)(xq)));
            v1 = tanhf(v1 + bf2f((unsigned short)(xq >> 16)));
            v2 = tanhf(v2 + bf2f((unsigned short)(xq >> 32)));
            v3 = tanhf(v3 + bf2f((unsigned short)(xq >> 48)));
            u64 o = pack4(v0, v1, v2, v3);
            unsigned short* hp = h0b + ((s & 1) * 131072) + ro;
            asm volatile("global_store_dwordx2 %0, %1, off sc0 sc1" :: "v"(hp), "v"(o) : "memory");
          } else if (layer == 1) {
            float4 bq = *(const float4*)&b1[gc];
            f32x4 o4; o4[0] = v0 + bq.x; o4[1] = v1 + bq.y; o4[2] = v2 + bq.z; o4[3] = v3 + bq.w;
            float* pp = px + (((s - 1) & 1) * 131072) + ro;
            asm volatile("global_store_dwordx4 %0, %1, off sc0 sc1" :: "v"(pp), "v"(o4) : "memory");
          } else {
            f32x4 pxf = u2f(pxq);
            v0 = tanhf(v0 + pxf[0]);
            v1 = tanhf(v1 + pxf[1]);
            v2 = tanhf(v2 + pxf[2]);
            v3 = tanhf(v3 + pxf[3]);
            u64 o = pack4(v0, v1, v2, v3);
            unsigned short* hp = h1b + (((s - 2) & 1) * 131072) + ro;
            asm volatile("global_store_dwordx2 %0, %1, off sc0 sc1" :: "v"(hp), "v"(o) : "memory");
            if (s == 81) {
              f32x4 f4; f4[0] = v0; f4[1] = v1; f4[2] = v2; f4[3] = v3;
              *(f32x4*)&h1f[ro] = f4;
            }
          }
        };
        do_item(r0, pxq0);
        do_item(r1, pxq1);
      }
      asm volatile("s_waitcnt vmcnt(0)" ::: "memory");
    }  // active

    __syncthreads();
    if (s < 81) {
      const int epoch = s + 1;
      if (tid == 0) st_flag(&bar[wg << 6], epoch);
      if (tid < NWG) {
        int guard = 0;
        while (ld_flag(&bar[tid << 6]) < epoch) {
          __builtin_amdgcn_s_sleep(2);
          if (++guard > (1 << 20)) break;
        }
      }
      __syncthreads();
    }
  }
}

// -------------------- output: sigmoid(h1 @ Wo + bo) --------------------
__global__ __launch_bounds__(256) void out_kernel(
    const float* __restrict__ h1f, const float* __restrict__ Wo,
    const float* __restrict__ bo, float* __restrict__ out) {
  const int b = blockIdx.x, tid = threadIdx.x;
  const float* row = h1f + (size_t)b * 2048u;
  float p = 0.f;
  for (int u = tid; u < 2048; u += 256) p += row[u] * Wo[u];
#pragma unroll
  for (int off = 32; off > 0; off >>= 1) p += __shfl_down(p, off, 64);
  __shared__ float wsum[4];
  if ((tid & 63) == 0) wsum[tid >> 6] = p;
  __syncthreads();
  if (tid == 0) {
    float sth = wsum[0] + wsum[1] + wsum[2] + wsum[3] + bo[0];
    out[b] = 1.f / (1.f + __expf(-sth));
  }
}

extern "C" void kernel_launch(void* const* d_in, const int* in_sizes, int n_in,
                              void* d_out, int out_size, void* d_ws, size_t ws_size,
                              hipStream_t stream) {
  (void)in_sizes; (void)n_in; (void)out_size;
  if (ws_size < (size_t)WS_NEEDED) return;  // would corrupt: bail (fails absmax loudly)

  const int*   inputs = (const int*)d_in[0];
  const float* emb    = (const float*)d_in[1];
  const float* Wx0    = (const float*)d_in[2];
  const float* Wh0    = (const float*)d_in[3];
  const float* b0     = (const float*)d_in[4];
  const float* Wx1    = (const float*)d_in[5];
  const float* Wh1    = (const float*)d_in[6];
  const float* b1     = (const float*)d_in[7];
  const float* Wo     = (const float*)d_in[8];
  const float* bo     = (const float*)d_in[9];
  float* out = (float*)d_out;
  char* ws = (char*)d_ws;

  unsigned short* xproj = (unsigned short*)(ws + XPROJ_OFF);
  unsigned short* wpack = (unsigned short*)(ws + WPACK_OFF);
  unsigned short* h0b   = (unsigned short*)(ws + H0_OFF);
  unsigned short* h1b   = (unsigned short*)(ws + H1_OFF);
  float* px   = (float*)(ws + PX_OFF);
  float* h1f  = (float*)(ws + H1F_OFF);
  int*   bar  = (int*)(ws + BAR_OFF);

  (void)hipFuncSetAttribute((const void*)rnn_persistent,
                            hipFuncAttributeMaxDynamicSharedMemorySize, LDS_BYTES);

  zero_init<<<256, 256, 0, stream>>>((u32x4*)(ws + H0_OFF), ZERO_U4);
  pack_weights<<<384, 256, 0, stream>>>(Wh0, Wx1, Wh1, wpack);
  xproj_kernel<<<dim3(32, 80), 256, 0, stream>>>(inputs, emb, Wx0, b0, xproj);
  rnn_persistent<<<NWG, 256, LDS_BYTES, stream>>>(xproj, wpack, h0b, h1b, px, h1f, b1, bar);
  out_kernel<<<64, 256, 0, stream>>>(h1f, Wo, bo, out);
}

// Round 6
// 1108.506 us; speedup vs baseline: 1.3718x; 1.3718x over previous
//
#include <hip/hip_runtime.h>

// Problem dims
#define BB 64
#define TT 80
#define EE 100
#define UU 2048
#define NWG 192

typedef float f32x4 __attribute__((ext_vector_type(4)));
typedef unsigned int u32x4 __attribute__((ext_vector_type(4)));
typedef __bf16 bf16x8 __attribute__((ext_vector_type(8)));
typedef unsigned long long u64;

// ---- workspace layout (bytes) ----
#define XPROJ_OFF 0u              // bf16 [80][64][2048]  = 20,971,520
#define WPACK_OFF 20971520u       // bf16 packed [192][4(kq)][16(kt)][2(c)][64][8] = 25,165,824
#define H0_OFF    46137344u       // bf16 [16][64][2048] = 4,194,304  (ring, slot 15 zero = h0[-1])
#define H1_OFF    50331648u       // bf16 [16][64][2048] = 4,194,304  (ring, slot 15 zero = h1[-1])
#define PX_OFF    54525952u       // f32  [8][64][2048]  = 4,194,304  (ring)
#define H1F_OFF   58720256u       // f32  [64][2048]     = 524,288
#define BAR_OFF   59244544u       // int flags padded: 192 * 256 B = 49,152
#define WS_NEEDED 59293696u
#define ZERO_U4   822272          // (WS_NEEDED - H0_OFF)/16

#define LDS_BYTES 147968          // 131072 weights + 2*64*33*4 red

__device__ __forceinline__ unsigned short f2bf(float f) {
  unsigned int u = __float_as_uint(f);
  u += 0x7fffu + ((u >> 16) & 1u);
  return (unsigned short)(u >> 16);
}
__device__ __forceinline__ float bf2f(unsigned short h) {
  return __uint_as_float(((unsigned int)h) << 16);
}
__device__ __forceinline__ u64 pack4(float a, float b, float c, float d) {
  return (u64)f2bf(a) | ((u64)f2bf(b) << 16) | ((u64)f2bf(c) << 32) | ((u64)f2bf(d) << 48);
}
__device__ __forceinline__ bf16x8 u2b(u32x4 u) {
  union { u32x4 q; bf16x8 b; } x; x.q = u; return x.b;
}
__device__ __forceinline__ f32x4 u2f(u32x4 u) {
  union { u32x4 q; f32x4 f; } x; x.q = u; return x.f;
}

// coherent (device-scope, L1+L2 bypass) flag ops
__device__ __forceinline__ void st_flag(int* p, int v) {
  asm volatile("global_store_dword %0, %1, off sc0 sc1" :: "v"(p), "v"(v) : "memory");
}
__device__ __forceinline__ int ld_flag(const int* p) {
  int r;
  asm volatile("global_load_dword %0, %1, off sc0 sc1\n\ts_waitcnt vmcnt(0)"
               : "=v"(r) : "v"(p) : "memory");
  return r;
}

// -------------------- zero init --------------------
__global__ void zero_init(u32x4* __restrict__ p, int n) {
  u32x4 z = {0u, 0u, 0u, 0u};
  for (int i = blockIdx.x * blockDim.x + threadIdx.x; i < n; i += gridDim.x * blockDim.x)
    p[i] = z;
}

// -------------------- weight pack --------------------
// dest elem: wg*65536 + kq*16384 + kt*1024 + c*512 + lane*8 + j
// value = W[k][col], k = kq*512 + kt*32 + (lane>>4)*8 + j, col = wl*32 + c*16 + (lane&15)
// wg = L*64 + wl ; L in {Wh0, Wx1, Wh1}
__global__ __launch_bounds__(256) void pack_weights(
    const float* __restrict__ Wh0, const float* __restrict__ Wx1,
    const float* __restrict__ Wh1, unsigned short* __restrict__ wpack) {
  __shared__ float tile[32][33];
  const int bb = blockIdx.x;             // 0..383
  const int L = bb >> 7;
  const int rest = bb & 127;
  const int wl = rest >> 1;
  const int kh = rest & 1;               // k half (1024)
  const float* src = (L == 0) ? Wh0 : (L == 1) ? Wx1 : Wh1;
  const int tid = threadIdx.x;
  const int kr = tid >> 3, cqr = tid & 7;          // read mapping
  const int c = tid >> 7;                           // write mapping
  const int lane = (tid >> 1) & 63;
  const int jh = (tid & 1) << 2;
  const int l16 = lane & 15, lq = lane >> 4;
  const size_t wg = (size_t)(L << 6) + wl;

  for (int kc = 0; kc < 32; ++kc) {
    const int kq = (kh << 1) + (kc >> 4);
    const int kt = kc & 15;
    const int k0 = (kh << 10) + (kc << 5);
    float4 v = *(const float4*)&src[(size_t)(k0 + kr) * 2048u + (wl << 5) + (cqr << 2)];
    tile[kr][cqr * 4 + 0] = v.x;
    tile[kr][cqr * 4 + 1] = v.y;
    tile[kr][cqr * 4 + 2] = v.z;
    tile[kr][cqr * 4 + 3] = v.w;
    __syncthreads();
    ushort4 o;
    o.x = f2bf(tile[lq * 8 + jh + 0][c * 16 + l16]);
    o.y = f2bf(tile[lq * 8 + jh + 1][c * 16 + l16]);
    o.z = f2bf(tile[lq * 8 + jh + 2][c * 16 + l16]);
    o.w = f2bf(tile[lq * 8 + jh + 3][c * 16 + l16]);
    size_t doff = (wg << 16) + ((size_t)kq << 14) + ((size_t)kt << 10) + (c << 9) + (lane << 3) + jh;
    *(ushort4*)&wpack[doff] = o;
    __syncthreads();
  }
}

// -------------------- xproj = emb[inputs] @ Wx0 + b0 (bf16 out) --------------------
__global__ __launch_bounds__(256) void xproj_kernel(
    const int* __restrict__ inputs, const float* __restrict__ emb,
    const float* __restrict__ Wx0, const float* __restrict__ b0,
    unsigned short* __restrict__ xp) {
  __shared__ float X[64][100];
  __shared__ float Wl[100][64];
  __shared__ int idx[64];
  const int t = blockIdx.y, ut = blockIdx.x, tid = threadIdx.x;
  if (tid < 64) idx[tid] = inputs[tid * TT + t];
  __syncthreads();
  for (int i = tid; i < 6400; i += 256) {
    int b = i / 100, e = i - b * 100;
    X[b][e] = emb[(size_t)idx[b] * EE + e];
  }
  for (int i = tid; i < 6400; i += 256) {
    int e = i >> 6, u = i & 63;
    Wl[e][u] = Wx0[(size_t)e * UU + (ut << 6) + u];
  }
  __syncthreads();
  const int ul = tid & 63, bg = tid >> 6;
  float accv[16];
  const float bias = b0[(ut << 6) + ul];
#pragma unroll
  for (int q = 0; q < 16; ++q) accv[q] = bias;
  for (int e4 = 0; e4 < 100; e4 += 4) {
    float w0 = Wl[e4 + 0][ul], w1 = Wl[e4 + 1][ul], w2 = Wl[e4 + 2][ul], w3 = Wl[e4 + 3][ul];
#pragma unroll
    for (int q = 0; q < 16; ++q) {
      float4 x4 = *(const float4*)&X[bg * 16 + q][e4];
      accv[q] += w0 * x4.x + w1 * x4.y + w2 * x4.z + w3 * x4.w;
    }
  }
  unsigned short* dst = xp + ((size_t)t * 64u) * 2048u + (ut << 6);
#pragma unroll
  for (int q = 0; q < 16; ++q) dst[(size_t)(bg * 16 + q) * 2048u + ul] = f2bf(accv[q]);
}

// -------------------- persistent RNN (dataflow-pipelined) --------------------
// 192 WGs: layer = wg>>6, wl = wg&63 -> cols [wl*32,+32). Each layer runs its OWN
// t = 0..79: L0: h0[t]=tanh(h0[t-1]@Wh0+xproj[t]); L1: px[t]=h0[t]@Wx1+b1;
// L2: h1[t]=tanh(h1[t-1]@Wh1+px[t]).
// Ring buffers: h0/h1 16 slots, px 8 slots. Lag-waits (flag = completed steps):
//   L0@t: L0>=t,   L1>=t-15   (RAW self-chain; WAR h0 slot reuse)
//   L1@t: L0>=t+1, L2>=t-7    (RAW h0[t];     WAR px slot reuse)
//   L2@t: L1>=t+1, L2>=t      (RAW px[t];     RAW h1 self-chain)
// Skew caps (15/7/1) < slot periods (16/8) + buffer_inv sc1 every 8 local steps
// guarantee no stale L1/L2 line can be re-read. A/px loads are CACHED (L2
// broadcast); producers store sc0 sc1 (write-through, L2 never dirty).
__global__ __launch_bounds__(256, 1) void rnn_persistent(
    const unsigned short* __restrict__ xproj, const unsigned short* __restrict__ wpack,
    unsigned short* __restrict__ h0b, unsigned short* __restrict__ h1b,
    float* __restrict__ px, float* __restrict__ h1f,
    const float* __restrict__ b1, int* __restrict__ bar) {
  extern __shared__ char smem[];
  unsigned short* wlds = (unsigned short*)smem;   // 131072 B: [wave(kq)][kt][c][lane][8]
  float* red = (float*)(smem + 131072);           // 2*64*33*4 = 16896 B
  const int wg = blockIdx.x, tid = threadIdx.x;
  const int wave = tid >> 6, lane = tid & 63;
  const int layer = wg >> 6, wl = wg & 63;
  const int l16 = lane & 15, lq = lane >> 4;
  const int colb = wl << 5;

  // stage this WG's packed weights into LDS (once)
  {
    const u32x4* srcp = (const u32x4*)(wpack + ((size_t)wg << 16));
    u32x4* dstp = (u32x4*)smem;
    for (int i = tid; i < 8192; i += 256) dstp[i] = srcp[i];
  }
  __syncthreads();

  const unsigned short* wbase = wlds + (wave << 14) + (lane << 3);
  // A element offset (this wave's K-quarter): row = rg*16+l16, k = wave*512 + lq*8
  const int aoff = l16 * 2048 + (wave << 9) + (lq << 3);
  // epilogue items
  const int r0 = tid >> 3, cq = tid & 7;
  const int r1 = r0 + 32;

  // wait groups/targets
  const int gA = (layer == 2) ? 1 : 0;
  const int gB = (layer == 0) ? 1 : 2;

  for (int t = 0; t < 80; ++t) {
    const int tgtA = (layer == 0) ? t : (t + 1);
    const int tgtB = (layer == 0) ? (t - 15) : (layer == 1) ? (t - 7) : t;

    // ---- lag-waits: wave0 polls group A, wave1 polls group B ----
    if (wave == 0) {
      if (tgtA > 0) {
        const int* p = bar + (((gA << 6) + lane) << 6);
        int guard = 0;
        while (ld_flag(p) < tgtA) {
          __builtin_amdgcn_s_sleep(1);
          if (++guard > (1 << 18)) break;
        }
      }
    } else if (wave == 1) {
      if (tgtB > 0) {
        const int* p = bar + (((gB << 6) + lane) << 6);
        int guard = 0;
        while (ld_flag(p) < tgtB) {
          __builtin_amdgcn_s_sleep(1);
          if (++guard > (1 << 18)) break;
        }
      }
    }
    __syncthreads();
    if ((t & 7) == 0) {
      asm volatile("buffer_inv sc1" ::: "memory");
    }

    // ---- A source (ring slots; slot 15 pre-zeroed = state[-1]) ----
    const unsigned short* Abuf =
        (layer == 0) ? (h0b + (size_t)((t + 15) & 15) * 131072u)
      : (layer == 1) ? (h0b + (size_t)(t & 15) * 131072u)
                     : (h1b + (size_t)((t + 15) & 15) * 131072u);
    const unsigned short* ap0 = Abuf + aoff;
    const unsigned short* ap1 = ap0 + 16 * 2048;
    const unsigned short* ap2 = ap0 + 32 * 2048;
    const unsigned short* ap3 = ap0 + 48 * 2048;

    u32x4 pxq0, pxq1;
    if (layer == 2) {
      const float* pxs = px + (size_t)(t & 7) * 131072u;
      const float* pp0 = pxs + r0 * 2048 + colb + (cq << 2);
      const float* pp1 = pxs + r1 * 2048 + colb + (cq << 2);
      asm volatile("global_load_dwordx4 %0, %2, off\n\t"
                   "global_load_dwordx4 %1, %3, off"
                   : "=v"(pxq0), "=v"(pxq1) : "v"(pp0), "v"(pp1) : "memory");
    }

    u32x4 Asl[8][4];
    f32x4 c00 = {0,0,0,0}, c01 = {0,0,0,0}, c10 = {0,0,0,0}, c11 = {0,0,0,0};
    f32x4 c20 = {0,0,0,0}, c21 = {0,0,0,0}, c30 = {0,0,0,0}, c31 = {0,0,0,0};

#define ISSUE(sl, koff) \
    asm volatile("global_load_dwordx4 %0, %4, off offset:" #koff "\n\t" \
                 "global_load_dwordx4 %1, %5, off offset:" #koff "\n\t" \
                 "global_load_dwordx4 %2, %6, off offset:" #koff "\n\t" \
                 "global_load_dwordx4 %3, %7, off offset:" #koff \
                 : "=v"(Asl[sl][0]), "=v"(Asl[sl][1]), "=v"(Asl[sl][2]), "=v"(Asl[sl][3]) \
                 : "v"(ap0), "v"(ap1), "v"(ap2), "v"(ap3) : "memory")

    ISSUE(0, 0);   ISSUE(1, 64);  ISSUE(2, 128); ISSUE(3, 192);
    ISSUE(4, 256); ISSUE(5, 320); ISSUE(6, 384); ISSUE(7, 448);

    bf16x8 cb0 = *(const bf16x8*)(wbase);
    bf16x8 cb1 = *(const bf16x8*)(wbase + 512);

#define MFMA8(sl) \
    c00 = __builtin_amdgcn_mfma_f32_16x16x32_bf16(u2b(Asl[sl][0]), cb0, c00, 0, 0, 0); \
    c10 = __builtin_amdgcn_mfma_f32_16x16x32_bf16(u2b(Asl[sl][1]), cb0, c10, 0, 0, 0); \
    c20 = __builtin_amdgcn_mfma_f32_16x16x32_bf16(u2b(Asl[sl][2]), cb0, c20, 0, 0, 0); \
    c30 = __builtin_amdgcn_mfma_f32_16x16x32_bf16(u2b(Asl[sl][3]), cb0, c30, 0, 0, 0); \
    c01 = __builtin_amdgcn_mfma_f32_16x16x32_bf16(u2b(Asl[sl][0]), cb1, c01, 0, 0, 0); \
    c11 = __builtin_amdgcn_mfma_f32_16x16x32_bf16(u2b(Asl[sl][1]), cb1, c11, 0, 0, 0); \
    c21 = __builtin_amdgcn_mfma_f32_16x16x32_bf16(u2b(Asl[sl][2]), cb1, c21, 0, 0, 0); \
    c31 = __builtin_amdgcn_mfma_f32_16x16x32_bf16(u2b(Asl[sl][3]), cb1, c31, 0, 0, 0)

#define KTI(kt, vN, koff) { \
    asm volatile("s_waitcnt vmcnt(" #vN ")" ::: "memory"); \
    __builtin_amdgcn_sched_barrier(0); \
    bf16x8 nb0 = *(const bf16x8*)(wbase + (kt + 1) * 1024); \
    bf16x8 nb1 = *(const bf16x8*)(wbase + (kt + 1) * 1024 + 512); \
    MFMA8((kt) & 7); \
    ISSUE((kt) & 7, koff); \
    cb0 = nb0; cb1 = nb1; }

#define KTN(kt, vN) { \
    asm volatile("s_waitcnt vmcnt(" #vN ")" ::: "memory"); \
    __builtin_amdgcn_sched_barrier(0); \
    bf16x8 nb0 = cb0, nb1 = cb1; \
    if ((kt) < 15) { nb0 = *(const bf16x8*)(wbase + (kt + 1) * 1024); \
                     nb1 = *(const bf16x8*)(wbase + (kt + 1) * 1024 + 512); } \
    MFMA8((kt) & 7); \
    cb0 = nb0; cb1 = nb1; }

    KTI(0, 28, 512); KTI(1, 28, 576); KTI(2, 28, 640); KTI(3, 28, 704);
    KTI(4, 28, 768); KTI(5, 28, 832); KTI(6, 28, 896); KTI(7, 28, 960);
    KTN(8, 28); KTN(9, 24); KTN(10, 20); KTN(11, 16);
    KTN(12, 12); KTN(13, 8); KTN(14, 4); KTN(15, 0);

#undef ISSUE
#undef MFMA8
#undef KTI
#undef KTN

    // ---- cross-wave K reduction (2-phase) ----
#define WRROW(cv, rg, cc) { int bi = ((rg)*16 + lq*4)*33 + (cc)*16 + l16; \
    rb[bi] = cv[0]; rb[bi+33] = cv[1]; rb[bi+66] = cv[2]; rb[bi+99] = cv[3]; }
#define ADROW(cv, rg, cc) { int bi = ((rg)*16 + lq*4)*33 + (cc)*16 + l16; \
    rb[bi] += cv[0]; rb[bi+33] += cv[1]; rb[bi+66] += cv[2]; rb[bi+99] += cv[3]; }
    if (wave < 2) {
      float* rb = red + wave * 2112;
      WRROW(c00, 0, 0); WRROW(c10, 1, 0); WRROW(c20, 2, 0); WRROW(c30, 3, 0);
      WRROW(c01, 0, 1); WRROW(c11, 1, 1); WRROW(c21, 2, 1); WRROW(c31, 3, 1);
    }
    __syncthreads();
    if (wave >= 2) {
      float* rb = red + (wave - 2) * 2112;
      ADROW(c00, 0, 0); ADROW(c10, 1, 0); ADROW(c20, 2, 0); ADROW(c30, 3, 0);
      ADROW(c01, 0, 1); ADROW(c11, 1, 1); ADROW(c21, 2, 1); ADROW(c31, 3, 1);
    }
    __syncthreads();
#undef WRROW
#undef ADROW

    // ---- epilogue: 2 items/thread ----
    {
      const int gc = colb + (cq << 2);
      auto do_item = [&](int r, u32x4 pxq) {
        const int c0 = cq << 2;
        float v0 = red[r * 33 + c0 + 0] + red[2112 + r * 33 + c0 + 0];
        float v1 = red[r * 33 + c0 + 1] + red[2112 + r * 33 + c0 + 1];
        float v2 = red[r * 33 + c0 + 2] + red[2112 + r * 33 + c0 + 2];
        float v3 = red[r * 33 + c0 + 3] + red[2112 + r * 33 + c0 + 3];
        const size_t ro = ((size_t)r << 11) + gc;
        if (layer == 0) {
          u64 xq = *(const u64*)(xproj + (size_t)t * 131072u + ro);
          v0 = tanhf(v0 + bf2f((unsigned short)(xq)));
          v1 = tanhf(v1 + bf2f((unsigned short)(xq >> 16)));
          v2 = tanhf(v2 + bf2f((unsigned short)(xq >> 32)));
          v3 = tanhf(v3 + bf2f((unsigned short)(xq >> 48)));
          u64 o = pack4(v0, v1, v2, v3);
          unsigned short* hp = h0b + (size_t)(t & 15) * 131072u + ro;
          asm volatile("global_store_dwordx2 %0, %1, off sc0 sc1" :: "v"(hp), "v"(o) : "memory");
        } else if (layer == 1) {
          float4 bq = *(const float4*)&b1[gc];
          f32x4 o4; o4[0] = v0 + bq.x; o4[1] = v1 + bq.y; o4[2] = v2 + bq.z; o4[3] = v3 + bq.w;
          float* pp = px + (size_t)(t & 7) * 131072u + ro;
          asm volatile("global_store_dwordx4 %0, %1, off sc0 sc1" :: "v"(pp), "v"(o4) : "memory");
        } else {
          f32x4 pxf = u2f(pxq);
          v0 = tanhf(v0 + pxf[0]);
          v1 = tanhf(v1 + pxf[1]);
          v2 = tanhf(v2 + pxf[2]);
          v3 = tanhf(v3 + pxf[3]);
          u64 o = pack4(v0, v1, v2, v3);
          unsigned short* hp = h1b + (size_t)(t & 15) * 131072u + ro;
          asm volatile("global_store_dwordx2 %0, %1, off sc0 sc1" :: "v"(hp), "v"(o) : "memory");
          if (t == 79) {
            f32x4 f4; f4[0] = v0; f4[1] = v1; f4[2] = v2; f4[3] = v3;
            *(f32x4*)&h1f[ro] = f4;
          }
        }
      };
      do_item(r0, pxq0);
      do_item(r1, pxq1);
    }
    asm volatile("s_waitcnt vmcnt(0)" ::: "memory");

    __syncthreads();
    if (tid == 0) st_flag(&bar[wg << 6], t + 1);
  }
}

// -------------------- output: sigmoid(h1 @ Wo + bo) --------------------
__global__ __launch_bounds__(256) void out_kernel(
    const float* __restrict__ h1f, const float* __restrict__ Wo,
    const float* __restrict__ bo, float* __restrict__ out) {
  const int b = blockIdx.x, tid = threadIdx.x;
  const float* row = h1f + (size_t)b * 2048u;
  float p = 0.f;
  for (int u = tid; u < 2048; u += 256) p += row[u] * Wo[u];
#pragma unroll
  for (int off = 32; off > 0; off >>= 1) p += __shfl_down(p, off, 64);
  __shared__ float wsum[4];
  if ((tid & 63) == 0) wsum[tid >> 6] = p;
  __syncthreads();
  if (tid == 0) {
    float sth = wsum[0] + wsum[1] + wsum[2] + wsum[3] + bo[0];
    out[b] = 1.f / (1.f + __expf(-sth));
  }
}

extern "C" void kernel_launch(void* const* d_in, const int* in_sizes, int n_in,
                              void* d_out, int out_size, void* d_ws, size_t ws_size,
                              hipStream_t stream) {
  (void)in_sizes; (void)n_in; (void)out_size;
  if (ws_size < (size_t)WS_NEEDED) return;  // would corrupt: bail (fails absmax loudly)

  const int*   inputs = (const int*)d_in[0];
  const float* emb    = (const float*)d_in[1];
  const float* Wx0    = (const float*)d_in[2];
  const float* Wh0    = (const float*)d_in[3];
  const float* b0     = (const float*)d_in[4];
  const float* Wx1    = (const float*)d_in[5];
  const float* Wh1    = (const float*)d_in[6];
  const float* b1     = (const float*)d_in[7];
  const float* Wo     = (const float*)d_in[8];
  const float* bo     = (const float*)d_in[9];
  float* out = (float*)d_out;
  char* ws = (char*)d_ws;

  unsigned short* xproj = (unsigned short*)(ws + XPROJ_OFF);
  unsigned short* wpack = (unsigned short*)(ws + WPACK_OFF);
  unsigned short* h0b   = (unsigned short*)(ws + H0_OFF);
  unsigned short* h1b   = (unsigned short*)(ws + H1_OFF);
  float* px   = (float*)(ws + PX_OFF);
  float* h1f  = (float*)(ws + H1F_OFF);
  int*   bar  = (int*)(ws + BAR_OFF);

  (void)hipFuncSetAttribute((const void*)rnn_persistent,
                            hipFuncAttributeMaxDynamicSharedMemorySize, LDS_BYTES);

  zero_init<<<256, 256, 0, stream>>>((u32x4*)(ws + H0_OFF), ZERO_U4);
  pack_weights<<<384, 256, 0, stream>>>(Wh0, Wx1, Wh1, wpack);
  xproj_kernel<<<dim3(32, 80), 256, 0, stream>>>(inputs, emb, Wx0, b0, xproj);
  rnn_persistent<<<NWG, 256, LDS_BYTES, stream>>>(xproj, wpack, h0b, h1b, px, h1f, b1, bar);
  out_kernel<<<64, 256, 0, stream>>>(h1f, Wo, bo, out);
}